// Round 1
// baseline (249.900 us; speedup 1.0000x reference)
//
#include <hip/hip_runtime.h>
#include <math.h>

// Input order (setup_inputs dict order):
// d_in[0]=cls_p3 [32,4,128,128], d_in[1]=reg_p3 [32,64,128,128],
// d_in[2]=cls_p4, d_in[3]=reg_p4, d_in[4]=cls_p5, d_in[5]=reg_p5,
// d_in[6]=cls_p6, d_in[7]=reg_p6, d_in[8]=targets [32,64,5]
// Output: 4 floats: total, cls_l, box_l, dfl_l
//
// Workspace layout (floats):
//   ws[0..31]  : nvalid[b]           (written by target_kernel, ballot count)
//   ws[33]     : adj sum   (atomic)
//   ws[34]     : box sum   (atomic)
//   ws[35]     : dfl sum   (atomic)
//   ws[36..36+K1_BLOCKS) : per-block partials of the cls base term

__device__ inline float waveReduceSum(float v) {
#pragma unroll
    for (int m = 32; m >= 1; m >>= 1) v += __shfl_xor(v, m, 64);
    return v;
}

__global__ __launch_bounds__(256) void target_kernel(
    const float* __restrict__ c0, const float* __restrict__ c1,
    const float* __restrict__ c2, const float* __restrict__ c3,
    const float* __restrict__ r0, const float* __restrict__ r1,
    const float* __restrict__ r2, const float* __restrict__ r3,
    const float* __restrict__ tgt, float* __restrict__ ws)
{
    // 8192 threads: tid -> (lvl, b, n); one wave = one (lvl,b), lanes = n
    int tid = blockIdx.x * 256 + threadIdx.x;
    int lvl = tid >> 11;
    int b   = (tid >> 6) & 31;
    int n   = tid & 63;

    const float* T = tgt + (b * 64 + n) * 5;
    float t0 = T[0], x1 = T[1], y1 = T[2], x2 = T[3], y2 = T[4];
    bool mask = t0 >= 0.f;

    // nvalid[b]: popcount of the wave's mask ballot (lvl 0 waves cover each b once)
    unsigned long long bal = __ballot(mask);
    if (lvl == 0 && (threadIdx.x & 63) == 0) ws[b] = (float)__popcll(bal);

    float cx = (x1 + x2) * 0.5f, cy = (y1 + y2) * 0.5f;
    int Wl = 128 >> lvl;
    int HW = Wl * Wl;
    float s = (float)(8 << lvl);
    float invs = 1.f / s;                       // s is pow2: exact, == division
    int gx = (int)(cx * invs); gx = min(max(gx, 0), Wl - 1);
    int gy = (int)(cy * invs); gy = min(max(gy, 0), Wl - 1);
    int cid = (int)fmaxf(t0, 0.f); cid = min(max(cid, 0), 3);

    const float* cp; const float* rp;
    if (lvl == 0)      { cp = c0; rp = r0; }
    else if (lvl == 1) { cp = c1; rp = r1; }
    else if (lvl == 2) { cp = c2; rp = r2; }
    else               { cp = c3; rp = r3; }

    int t = gy * Wl + gx;
    // logits row t of flat [4,H,W]: contiguous 4-chunk at flat index 4t
    const float* cb = cp + ((size_t)b * 4 * HW + 4 * t);
    float adj = (cb[0] - cb[cid]) / (float)HW;

    const float* rb = rp + ((size_t)b * 64 * HW + t);
    float tx = (cx - (float)gx * s) * invs;
    float ty = (cy - (float)gy * s) * invs;
    float treg[4] = { tx, ty, (x2 - x1) * invs, (y2 - y1) * invs };

    float boxsum = 0.f, dflsum = 0.f;
#pragma unroll
    for (int d = 0; d < 4; ++d) {
        float tr = treg[d];
        float s16 = 0.f;
#pragma unroll
        for (int m = 0; m < 16; ++m) {
            float v = rb[(size_t)(d * 16 + m) * HW];
            s16 += v;
            dflsum += fabsf(v - tr);
        }
        boxsum += fabsf(s16 * (1.f / 16.f) - tr);
    }
    float box_per = boxsum * 0.25f;
    float dfl_per = dflsum * (1.f / 64.f);
    if (!mask) { adj = 0.f; box_per = 0.f; dfl_per = 0.f; }

    // block reduce the three sums -> 3 atomics per block (32 blocks)
    __shared__ float red[4][3];
    float wa = waveReduceSum(adj);
    float wb = waveReduceSum(box_per);
    float wd = waveReduceSum(dfl_per);
    int lane = threadIdx.x & 63, wid = threadIdx.x >> 6;
    if (lane == 0) { red[wid][0] = wa; red[wid][1] = wb; red[wid][2] = wd; }
    __syncthreads();
    if (threadIdx.x == 0) {
        atomicAdd(&ws[33], red[0][0] + red[1][0] + red[2][0] + red[3][0]);
        atomicAdd(&ws[34], red[0][1] + red[1][1] + red[2][1] + red[3][1]);
        atomicAdd(&ws[35], red[0][2] + red[1][2] + red[2][2] + red[3][2]);
    }
}

__global__ __launch_bounds__(256) void base_kernel(
    const float* __restrict__ c0, const float* __restrict__ c1,
    const float* __restrict__ c2, const float* __restrict__ c3,
    const float* __restrict__ nvalid, float* __restrict__ partials)
{
    constexpr int E0 = 32 * 16384;        // level-0 cells
    constexpr int E1 = E0 + 32 * 4096;
    constexpr int E2 = E1 + 32 * 1024;
    constexpr int E3 = E2 + 32 * 256;     // 696320 total

    float acc = 0.f;
    int stride = gridDim.x * 256;
    for (int c = blockIdx.x * 256 + threadIdx.x; c < E3; c += stride) {
        const float* p; int local; int lg; float invHW;
        if (c < E0)      { p = c0; local = c;      lg = 14; invHW = 1.f / 16384.f; }
        else if (c < E1) { p = c1; local = c - E0; lg = 12; invHW = 1.f / 4096.f; }
        else if (c < E2) { p = c2; local = c - E1; lg = 10; invHW = 1.f / 1024.f; }
        else             { p = c3; local = c - E2; lg = 8;  invHW = 1.f / 256.f; }
        // cell 'local' = (b, r): flat [4,H,W] row r is float4 at index (b*HW + r) == local
        float4 v = ((const float4*)p)[local];
        float mx = fmaxf(fmaxf(v.x, v.y), fmaxf(v.z, v.w));
        float lse = logf(expf(v.x - mx) + expf(v.y - mx) +
                         expf(v.z - mx) + expf(v.w - mx)) + mx;
        acc += (lse - v.x) * nvalid[local >> lg] * invHW;
    }

    float w = waveReduceSum(acc);
    __shared__ float red[4];
    int lane = threadIdx.x & 63, wid = threadIdx.x >> 6;
    if (lane == 0) red[wid] = w;
    __syncthreads();
    if (threadIdx.x == 0)
        partials[blockIdx.x] = red[0] + red[1] + red[2] + red[3];
}

__global__ __launch_bounds__(256) void finalize_kernel(
    const float* __restrict__ ws, const float* __restrict__ partials,
    int np, float* __restrict__ out)
{
    float acc = 0.f;
    for (int i = threadIdx.x; i < np; i += 256) acc += partials[i];
    float w = waveReduceSum(acc);
    __shared__ float red[4];
    int lane = threadIdx.x & 63, wid = threadIdx.x >> 6;
    if (lane == 0) red[wid] = w;
    __syncthreads();
    if (threadIdx.x == 0) {
        float base = red[0] + red[1] + red[2] + red[3];
        float cls = base + ws[33];
        float box = ws[34];
        float dfl = ws[35];
        out[0] = 0.3f * cls + 8.f * box + 1.5f * dfl;
        out[1] = cls;
        out[2] = box;
        out[3] = dfl;
    }
}

extern "C" void kernel_launch(void* const* d_in, const int* in_sizes, int n_in,
                              void* d_out, int out_size, void* d_ws, size_t ws_size,
                              hipStream_t stream) {
    const float* c0 = (const float*)d_in[0];
    const float* r0 = (const float*)d_in[1];
    const float* c1 = (const float*)d_in[2];
    const float* r1 = (const float*)d_in[3];
    const float* c2 = (const float*)d_in[4];
    const float* r2 = (const float*)d_in[5];
    const float* c3 = (const float*)d_in[6];
    const float* r3 = (const float*)d_in[7];
    const float* tgt = (const float*)d_in[8];
    float* ws = (float*)d_ws;
    float* out = (float*)d_out;

    constexpr int K1_BLOCKS = 1024;

    hipMemsetAsync(d_ws, 0, 36 * sizeof(float), stream);
    target_kernel<<<32, 256, 0, stream>>>(c0, c1, c2, c3, r0, r1, r2, r3, tgt, ws);
    base_kernel<<<K1_BLOCKS, 256, 0, stream>>>(c0, c1, c2, c3, ws, ws + 36);
    finalize_kernel<<<1, 256, 0, stream>>>(ws, ws + 36, K1_BLOCKS, out);
}

// Round 2
// 236.516 us; speedup vs baseline: 1.0566x; 1.0566x over previous
//
#include <hip/hip_runtime.h>
#include <math.h>

// Input order (setup_inputs dict order):
// d_in[0]=cls_p3 [32,4,128,128], d_in[1]=reg_p3 [32,64,128,128],
// d_in[2]=cls_p4, d_in[3]=reg_p4, d_in[4]=cls_p5, d_in[5]=reg_p5,
// d_in[6]=cls_p6, d_in[7]=reg_p6, d_in[8]=targets [32,64,5]
// Output: 4 floats: total, cls_l, box_l, dfl_l
//
// Workspace layout (floats):
//   ws[0..31]  : nvalid[b]  (atomicAdd from lvl-0 target blocks)
//   ws[33]     : adj sum    (atomic)
//   ws[34]     : box sum    (atomic)
//   ws[35]     : dfl sum    (atomic)
//   ws[36..36+K1_BLOCKS) : per-block partials of the cls base term

__device__ inline float waveReduceSum(float v) {
#pragma unroll
    for (int m = 32; m >= 1; m >>= 1) v += __shfl_xor(v, m, 64);
    return v;
}

// One block per (lvl, b, target-group-of-16). Thread = (n_local, d, q):
// n_local = tid>>4 (16 targets), d = (tid>>2)&3 (box side), q = tid&3
// (quartet of the 16 DFL bins). 4 scattered loads per thread instead of 64
// -> 16x the memory-level parallelism of the previous version.
__global__ __launch_bounds__(256) void target_kernel(
    const float* __restrict__ c0, const float* __restrict__ c1,
    const float* __restrict__ c2, const float* __restrict__ c3,
    const float* __restrict__ r0, const float* __restrict__ r1,
    const float* __restrict__ r2, const float* __restrict__ r3,
    const float* __restrict__ tgt, float* __restrict__ ws)
{
    int lvl = blockIdx.x >> 7;          // 4 levels x 128 blocks each
    int rem = blockIdx.x & 127;
    int b   = rem >> 2;                 // 32 batches
    int g   = rem & 3;                  // 4 groups of 16 targets

    int tid = threadIdx.x;
    int n_local = tid >> 4;
    int d = (tid >> 2) & 3;
    int q = tid & 3;
    int n = g * 16 + n_local;

    const float* T = tgt + (b * 64 + n) * 5;
    float t0 = T[0], x1 = T[1], y1 = T[2], x2 = T[3], y2 = T[4];
    bool mask = t0 >= 0.f;

    float cx = (x1 + x2) * 0.5f, cy = (y1 + y2) * 0.5f;
    int Wl = 128 >> lvl;
    int HW = Wl * Wl;
    float s = (float)(8 << lvl);
    float invs = 1.f / s;                     // s is pow2: exact
    int gx = (int)(cx * invs); gx = min(max(gx, 0), Wl - 1);
    int gy = (int)(cy * invs); gy = min(max(gy, 0), Wl - 1);
    int cid = (int)fmaxf(t0, 0.f); cid = min(max(cid, 0), 3);

    const float* cp; const float* rp;
    if (lvl == 0)      { cp = c0; rp = r0; }
    else if (lvl == 1) { cp = c1; rp = r1; }
    else if (lvl == 2) { cp = c2; rp = r2; }
    else               { cp = c3; rp = r3; }

    int t = gy * Wl + gx;

    // target regression values for this thread's side d
    float tx = (cx - (float)gx * s) * invs;
    float ty = (cy - (float)gy * s) * invs;
    float tr = (d == 0) ? tx : (d == 1) ? ty
             : (d == 2) ? (x2 - x1) * invs : (y2 - y1) * invs;

    // 4 scattered loads: bins q*4..q*4+3 of side d
    const float* rb = rp + ((size_t)b * 64 * HW + t);
    float v0 = rb[(size_t)(d * 16 + q * 4 + 0) * HW];
    float v1 = rb[(size_t)(d * 16 + q * 4 + 1) * HW];
    float v2 = rb[(size_t)(d * 16 + q * 4 + 2) * HW];
    float v3 = rb[(size_t)(d * 16 + q * 4 + 3) * HW];

    float s4 = v0 + v1 + v2 + v3;
    float dfl_c = fabsf(v0 - tr) + fabsf(v1 - tr) +
                  fabsf(v2 - tr) + fabsf(v3 - tr);
    // reassemble the 16-bin sum inside the lane quartet (q = tid bits [1:0])
    float s8  = s4 + __shfl_xor(s4, 1, 64);
    float s16 = s8 + __shfl_xor(s8, 2, 64);

    float box_c = 0.f, adj_c = 0.f, nv_c = 0.f;
    if (q == 0) {
        box_c = fabsf(s16 * (1.f / 16.f) - tr) * 0.25f;   // /4: mean over d
        if (d == 0) {
            const float* cb = cp + ((size_t)b * 4 * HW + 4 * t);
            adj_c = (cb[0] - cb[cid]) / (float)HW;
            nv_c = mask ? 1.f : 0.f;
        }
    }
    if (!mask) { adj_c = 0.f; box_c = 0.f; dfl_c = 0.f; }
    dfl_c *= (1.f / 64.f);   // per-target dfl = sum of 64 |.| / 64

    // block reduce 4 values -> atomics
    float ra = waveReduceSum(adj_c);
    float rbx = waveReduceSum(box_c);
    float rd = waveReduceSum(dfl_c);
    float rn = waveReduceSum(nv_c);
    __shared__ float red[4][4];
    int lane = tid & 63, wid = tid >> 6;
    if (lane == 0) { red[wid][0] = ra; red[wid][1] = rbx;
                     red[wid][2] = rd; red[wid][3] = rn; }
    __syncthreads();
    if (tid == 0) {
        atomicAdd(&ws[33], red[0][0] + red[1][0] + red[2][0] + red[3][0]);
        atomicAdd(&ws[34], red[0][1] + red[1][1] + red[2][1] + red[3][1]);
        atomicAdd(&ws[35], red[0][2] + red[1][2] + red[2][2] + red[3][2]);
        if (lvl == 0)
            atomicAdd(&ws[b], red[0][3] + red[1][3] + red[2][3] + red[3][3]);
    }
}

__global__ __launch_bounds__(256) void base_kernel(
    const float* __restrict__ c0, const float* __restrict__ c1,
    const float* __restrict__ c2, const float* __restrict__ c3,
    const float* __restrict__ nvalid, float* __restrict__ partials)
{
    constexpr int E0 = 32 * 16384;        // level-0 cells
    constexpr int E1 = E0 + 32 * 4096;
    constexpr int E2 = E1 + 32 * 1024;
    constexpr int E3 = E2 + 32 * 256;     // 696320 total

    float acc = 0.f;
    int stride = gridDim.x * 256;
    for (int c = blockIdx.x * 256 + threadIdx.x; c < E3; c += stride) {
        const float* p; int local; int lg; float invHW;
        if (c < E0)      { p = c0; local = c;      lg = 14; invHW = 1.f / 16384.f; }
        else if (c < E1) { p = c1; local = c - E0; lg = 12; invHW = 1.f / 4096.f; }
        else if (c < E2) { p = c2; local = c - E1; lg = 10; invHW = 1.f / 1024.f; }
        else             { p = c3; local = c - E2; lg = 8;  invHW = 1.f / 256.f; }
        // cell 'local' = (b, r): flat [4,H,W] row r is float4 at index (b*HW + r) == local
        float4 v = ((const float4*)p)[local];
        float mx = fmaxf(fmaxf(v.x, v.y), fmaxf(v.z, v.w));
        float lse = logf(expf(v.x - mx) + expf(v.y - mx) +
                         expf(v.z - mx) + expf(v.w - mx)) + mx;
        acc += (lse - v.x) * nvalid[local >> lg] * invHW;
    }

    float w = waveReduceSum(acc);
    __shared__ float red[4];
    int lane = threadIdx.x & 63, wid = threadIdx.x >> 6;
    if (lane == 0) red[wid] = w;
    __syncthreads();
    if (threadIdx.x == 0)
        partials[blockIdx.x] = red[0] + red[1] + red[2] + red[3];
}

__global__ __launch_bounds__(256) void finalize_kernel(
    const float* __restrict__ ws, const float* __restrict__ partials,
    int np, float* __restrict__ out)
{
    float acc = 0.f;
    for (int i = threadIdx.x; i < np; i += 256) acc += partials[i];
    float w = waveReduceSum(acc);
    __shared__ float red[4];
    int lane = threadIdx.x & 63, wid = threadIdx.x >> 6;
    if (lane == 0) red[wid] = w;
    __syncthreads();
    if (threadIdx.x == 0) {
        float base = red[0] + red[1] + red[2] + red[3];
        float cls = base + ws[33];
        float box = ws[34];
        float dfl = ws[35];
        out[0] = 0.3f * cls + 8.f * box + 1.5f * dfl;
        out[1] = cls;
        out[2] = box;
        out[3] = dfl;
    }
}

extern "C" void kernel_launch(void* const* d_in, const int* in_sizes, int n_in,
                              void* d_out, int out_size, void* d_ws, size_t ws_size,
                              hipStream_t stream) {
    const float* c0 = (const float*)d_in[0];
    const float* r0 = (const float*)d_in[1];
    const float* c1 = (const float*)d_in[2];
    const float* r1 = (const float*)d_in[3];
    const float* c2 = (const float*)d_in[4];
    const float* r2 = (const float*)d_in[5];
    const float* c3 = (const float*)d_in[6];
    const float* r3 = (const float*)d_in[7];
    const float* tgt = (const float*)d_in[8];
    float* ws = (float*)d_ws;
    float* out = (float*)d_out;

    constexpr int K1_BLOCKS = 1024;

    hipMemsetAsync(d_ws, 0, 36 * sizeof(float), stream);
    target_kernel<<<512, 256, 0, stream>>>(c0, c1, c2, c3, r0, r1, r2, r3, tgt, ws);
    base_kernel<<<K1_BLOCKS, 256, 0, stream>>>(c0, c1, c2, c3, ws, ws + 36);
    finalize_kernel<<<1, 256, 0, stream>>>(ws, ws + 36, K1_BLOCKS, out);
}

// Round 3
// 218.585 us; speedup vs baseline: 1.1433x; 1.0820x over previous
//
#include <hip/hip_runtime.h>
#include <math.h>

// Input order (setup_inputs dict order):
// d_in[0]=cls_p3 [32,4,128,128], d_in[1]=reg_p3 [32,64,128,128],
// d_in[2]=cls_p4, d_in[3]=reg_p4, d_in[4]=cls_p5, d_in[5]=reg_p5,
// d_in[6]=cls_p6, d_in[7]=reg_p6, d_in[8]=targets [32,64,5]
// Output: 4 floats: total, cls_l, box_l, dfl_l
//
// NO memset / atomic-accumulator: every block writes its partial float4
// unconditionally to ws; finalize reduces them. ws needs no init.
//   ws[4*blk .. 4*blk+3] = (base, adj, box, dfl) partial of block blk
// Grid: NBLK = 512 target-role + 256 base-role blocks.

#define TGT_BLOCKS 512
#define BASE_BLOCKS 256
#define NBLK (TGT_BLOCKS + BASE_BLOCKS)

__device__ inline float waveReduceSum(float v) {
#pragma unroll
    for (int m = 32; m >= 1; m >>= 1) v += __shfl_xor(v, m, 64);
    return v;
}

__global__ __launch_bounds__(256) void fused_kernel(
    const float* __restrict__ c0, const float* __restrict__ c1,
    const float* __restrict__ c2, const float* __restrict__ c3,
    const float* __restrict__ r0, const float* __restrict__ r1,
    const float* __restrict__ r2, const float* __restrict__ r3,
    const float* __restrict__ tgt, float4* __restrict__ partials)
{
    int tid = threadIdx.x;
    float4 part = make_float4(0.f, 0.f, 0.f, 0.f);   // (base, adj, box, dfl)

    if (blockIdx.x < TGT_BLOCKS) {
        // ---- target role: block = (lvl, b, group-of-16 targets) ----
        int lvl = blockIdx.x >> 7;          // 4 levels x 128 blocks
        int rem = blockIdx.x & 127;
        int b   = rem >> 2;
        int g   = rem & 3;
        int n_local = tid >> 4;             // 16 targets
        int d = (tid >> 2) & 3;             // box side
        int q = tid & 3;                    // quartet of the 16 DFL bins
        int n = g * 16 + n_local;

        const float* T = tgt + (b * 64 + n) * 5;
        float t0 = T[0], x1 = T[1], y1 = T[2], x2 = T[3], y2 = T[4];
        bool mask = t0 >= 0.f;

        float cx = (x1 + x2) * 0.5f, cy = (y1 + y2) * 0.5f;
        int Wl = 128 >> lvl;
        int HW = Wl * Wl;
        float s = (float)(8 << lvl);
        float invs = 1.f / s;               // s is pow2: exact
        int gx = (int)(cx * invs); gx = min(max(gx, 0), Wl - 1);
        int gy = (int)(cy * invs); gy = min(max(gy, 0), Wl - 1);
        int cid = (int)fmaxf(t0, 0.f); cid = min(max(cid, 0), 3);

        const float* cp; const float* rp;
        if (lvl == 0)      { cp = c0; rp = r0; }
        else if (lvl == 1) { cp = c1; rp = r1; }
        else if (lvl == 2) { cp = c2; rp = r2; }
        else               { cp = c3; rp = r3; }

        int t = gy * Wl + gx;
        float tx = (cx - (float)gx * s) * invs;
        float ty = (cy - (float)gy * s) * invs;
        float tr = (d == 0) ? tx : (d == 1) ? ty
                 : (d == 2) ? (x2 - x1) * invs : (y2 - y1) * invs;

        const float* rb = rp + ((size_t)b * 64 * HW + t);
        float v0 = rb[(size_t)(d * 16 + q * 4 + 0) * HW];
        float v1 = rb[(size_t)(d * 16 + q * 4 + 1) * HW];
        float v2 = rb[(size_t)(d * 16 + q * 4 + 2) * HW];
        float v3 = rb[(size_t)(d * 16 + q * 4 + 3) * HW];

        float s4 = v0 + v1 + v2 + v3;
        float dfl_c = fabsf(v0 - tr) + fabsf(v1 - tr) +
                      fabsf(v2 - tr) + fabsf(v3 - tr);
        float s8  = s4 + __shfl_xor(s4, 1, 64);
        float s16 = s8 + __shfl_xor(s8, 2, 64);

        float box_c = 0.f, adj_c = 0.f;
        if (q == 0) {
            box_c = fabsf(s16 * (1.f / 16.f) - tr) * 0.25f;  // /4: mean over d
            if (d == 0) {
                const float* cb = cp + ((size_t)b * 4 * HW + 4 * t);
                adj_c = (cb[0] - cb[cid]) / (float)HW;
            }
        }
        if (!mask) { adj_c = 0.f; box_c = 0.f; dfl_c = 0.f; }
        dfl_c *= (1.f / 64.f);

        part.y = waveReduceSum(adj_c);
        part.z = waveReduceSum(box_c);
        part.w = waveReduceSum(dfl_c);
    } else {
        // ---- base role: full-grid weighted logsumexp ----
        // local nvalid[32] from targets (L2-hot 8KB): thread -> 8 consecutive
        // (b,n) pairs, all within one b (8 | 64).
        __shared__ float nv[32];
        {
            int c = 0;
#pragma unroll
            for (int k = 0; k < 8; ++k)
                c += (tgt[(tid * 8 + k) * 5] >= 0.f) ? 1 : 0;
            float f = (float)c;
            f += __shfl_xor(f, 1, 64);
            f += __shfl_xor(f, 2, 64);
            f += __shfl_xor(f, 4, 64);     // sum over the 8 lanes sharing b
            if ((tid & 7) == 0) nv[tid >> 3] = f;
        }
        __syncthreads();

        constexpr int E0 = 32 * 16384;
        constexpr int E1 = E0 + 32 * 4096;
        constexpr int E2 = E1 + 32 * 1024;
        constexpr int E3 = E2 + 32 * 256;   // 696320 cells

        float acc = 0.f;
        int stride = BASE_BLOCKS * 256;
        for (int c = (blockIdx.x - TGT_BLOCKS) * 256 + tid; c < E3; c += stride) {
            const float* p; int local; int lg; float invHW;
            if (c < E0)      { p = c0; local = c;      lg = 14; invHW = 1.f / 16384.f; }
            else if (c < E1) { p = c1; local = c - E0; lg = 12; invHW = 1.f / 4096.f; }
            else if (c < E2) { p = c2; local = c - E1; lg = 10; invHW = 1.f / 1024.f; }
            else             { p = c3; local = c - E2; lg = 8;  invHW = 1.f / 256.f; }
            float4 v = ((const float4*)p)[local];
            float mx = fmaxf(fmaxf(v.x, v.y), fmaxf(v.z, v.w));
            float lse = logf(expf(v.x - mx) + expf(v.y - mx) +
                             expf(v.z - mx) + expf(v.w - mx)) + mx;
            acc += (lse - v.x) * nv[local >> lg] * invHW;
        }
        part.x = waveReduceSum(acc);
    }

    // block reduce the wave partials -> one float4 store per block
    __shared__ float4 red[4];
    int lane = tid & 63, wid = tid >> 6;
    if (lane == 0) red[wid] = part;
    __syncthreads();
    if (tid == 0) {
        float4 a = red[0], bq = red[1], cq = red[2], dq = red[3];
        partials[blockIdx.x] = make_float4(a.x + bq.x + cq.x + dq.x,
                                           a.y + bq.y + cq.y + dq.y,
                                           a.z + bq.z + cq.z + dq.z,
                                           a.w + bq.w + cq.w + dq.w);
    }
}

__global__ __launch_bounds__(256) void finalize_kernel(
    const float4* __restrict__ partials, float* __restrict__ out)
{
    int tid = threadIdx.x;
    float bx = 0.f, by = 0.f, bz = 0.f, bw = 0.f;
    for (int i = tid; i < NBLK; i += 256) {
        float4 v = partials[i];
        bx += v.x; by += v.y; bz += v.z; bw += v.w;
    }
    bx = waveReduceSum(bx);
    by = waveReduceSum(by);
    bz = waveReduceSum(bz);
    bw = waveReduceSum(bw);
    __shared__ float4 red[4];
    int lane = tid & 63, wid = tid >> 6;
    if (lane == 0) red[wid] = make_float4(bx, by, bz, bw);
    __syncthreads();
    if (tid == 0) {
        float base = red[0].x + red[1].x + red[2].x + red[3].x;
        float adj  = red[0].y + red[1].y + red[2].y + red[3].y;
        float box  = red[0].z + red[1].z + red[2].z + red[3].z;
        float dfl  = red[0].w + red[1].w + red[2].w + red[3].w;
        float cls = base + adj;
        out[0] = 0.3f * cls + 8.f * box + 1.5f * dfl;
        out[1] = cls;
        out[2] = box;
        out[3] = dfl;
    }
}

extern "C" void kernel_launch(void* const* d_in, const int* in_sizes, int n_in,
                              void* d_out, int out_size, void* d_ws, size_t ws_size,
                              hipStream_t stream) {
    const float* c0 = (const float*)d_in[0];
    const float* r0 = (const float*)d_in[1];
    const float* c1 = (const float*)d_in[2];
    const float* r1 = (const float*)d_in[3];
    const float* c2 = (const float*)d_in[4];
    const float* r2 = (const float*)d_in[5];
    const float* c3 = (const float*)d_in[6];
    const float* r3 = (const float*)d_in[7];
    const float* tgt = (const float*)d_in[8];
    float4* partials = (float4*)d_ws;
    float* out = (float*)d_out;

    fused_kernel<<<NBLK, 256, 0, stream>>>(c0, c1, c2, c3, r0, r1, r2, r3,
                                           tgt, partials);
    finalize_kernel<<<1, 256, 0, stream>>>(partials, out);
}